// Round 20
// baseline (139.809 us; speedup 1.0000x reference)
//
#include <hip/hip_runtime.h>
#include <hip/hip_bf16.h>
#include <math.h>

typedef short short8 __attribute__((ext_vector_type(8)));
typedef float f32x4 __attribute__((ext_vector_type(4)));
typedef int i32x4 __attribute__((ext_vector_type(4)));

#define NN 8192
#define FIN 256
#define FOUT 128
#define LRELU_A 0.2f
#define L2E 1.44269504088896f

__device__ __forceinline__ short f2bf(float x) {
    unsigned u = __builtin_bit_cast(unsigned, x);
    unsigned r = (u + 0x7FFFu + ((u >> 16) & 1u)) >> 16;   // RNE
    return (short)r;
}

__device__ __forceinline__ short f2bf_fast(float x) {
    return __builtin_bit_cast(short, __float2bfloat16(x));
}

__device__ __forceinline__ float bf2f(short s) {
    return __builtin_bit_cast(float, (int)((unsigned short)s) << 16);
}

__device__ __forceinline__ unsigned pack8(i32x4 a, i32x4 b) {
    return (unsigned)(a.x & 1)        | ((unsigned)(a.y & 1) << 1) |
           ((unsigned)(a.z & 1) << 2) | ((unsigned)(a.w & 1) << 3) |
           ((unsigned)(b.x & 1) << 4) | ((unsigned)(b.y & 1) << 5) |
           ((unsigned)(b.z & 1) << 6) | ((unsigned)(b.w & 1) << 7);
}

// K1: prep = Wh = h@W -> WhT bf16 (LDS-transposed, coalesced 16B writes;
// XCD-swizzled rows) + f1/f2. adj packing now lives inside k_attn.
__global__ __launch_bounds__(256) void k_prep(const float* __restrict__ h,
                                              const float* __restrict__ W,
                                              const float* __restrict__ a,
                                              short* __restrict__ WhT,
                                              float* __restrict__ f1,
                                              float* __restrict__ f2) {
    __shared__ float hs[8][FIN];
    const int tid = threadIdx.x;
    const int bid = blockIdx.x;

    const int swz = (bid & 7) * 128 + (bid >> 3);   // bijective on [0,1024)
    const int r0 = swz * 8;
    #pragma unroll
    for (int i = 0; i < 2; ++i) {
        int f4 = tid + 256 * i;
        int row = f4 >> 6;
        int k4 = (f4 & 63) << 2;
        *(float4*)&hs[row][k4] = *(const float4*)(h + (size_t)(r0 + row) * FIN + k4);
    }
    __syncthreads();
    const int c4 = (tid & 31) * 4;
    const int row = tid >> 5;
    float acc0 = 0.f, acc1 = 0.f, acc2 = 0.f, acc3 = 0.f;
    #pragma unroll 4
    for (int k = 0; k < FIN; ++k) {
        float hv = hs[row][k];
        float4 w4 = *(const float4*)(W + (size_t)k * FOUT + c4);
        acc0 = fmaf(hv, w4.x, acc0);
        acc1 = fmaf(hv, w4.y, acc1);
        acc2 = fmaf(hv, w4.z, acc2);
        acc3 = fmaf(hv, w4.w, acc3);
    }
    const int wr = r0 + row;

    // transpose through LDS (reuse hs): tws[col][row8], then 16B writes
    __syncthreads();                      // all hs reads complete
    short (*tws)[8] = (short (*)[8])hs;
    tws[c4 + 0][row] = f2bf(acc0);
    tws[c4 + 1][row] = f2bf(acc1);
    tws[c4 + 2][row] = f2bf(acc2);
    tws[c4 + 3][row] = f2bf(acc3);

    float4 a1v = *(const float4*)(a + c4);
    float4 a2v = *(const float4*)(a + FOUT + c4);
    float p1 = acc0 * a1v.x + acc1 * a1v.y + acc2 * a1v.z + acc3 * a1v.w;
    float p2 = acc0 * a2v.x + acc1 * a2v.y + acc2 * a2v.z + acc3 * a2v.w;
    #pragma unroll
    for (int m = 1; m <= 16; m <<= 1) {
        p1 += __shfl_xor(p1, m, 64);
        p2 += __shfl_xor(p2, m, 64);
    }
    if ((tid & 31) == 0) {
        f1[wr] = p1;
        f2[wr] = p2;
    }

    __syncthreads();                      // tws writes complete
    if (tid < FOUT)
        *(short8*)(WhT + (size_t)tid * NN + r0) = *(const short8*)tws[tid];
}

// body: 32 cols. fv = raw f2. u = fma(L2E,fv,c1), v = fma(0.2*L2E,fv,c2),
// p = exp2(max(u,v)), mask, bf16; 8 MFMA + 1 ones-MFMA (den = P@1).
__device__ __forceinline__ void gat_body(const short* __restrict__ lrd, unsigned m8,
                                         float4 fa, float4 fb,
                                         float c1, float c2,
                                         f32x4 acc[9], short8 ones) {
    short8 b0 = *(const short8*)(lrd + 0 * 1024);
    short8 b1 = *(const short8*)(lrd + 1 * 1024);
    short8 b2 = *(const short8*)(lrd + 2 * 1024);
    short8 b3 = *(const short8*)(lrd + 3 * 1024);
    short8 b4 = *(const short8*)(lrd + 4 * 1024);
    short8 b5 = *(const short8*)(lrd + 5 * 1024);
    short8 b6 = *(const short8*)(lrd + 6 * 1024);
    short8 b7 = *(const short8*)(lrd + 7 * 1024);

    float fv[8] = {fa.x, fa.y, fa.z, fa.w, fb.x, fb.y, fb.z, fb.w};
    short8 af;
    #pragma unroll
    for (int i = 0; i < 8; ++i) {
        float u = fmaf(L2E, fv[i], c1);
        float v = fmaf(LRELU_A * L2E, fv[i], c2);
        float p = __builtin_amdgcn_exp2f(fmaxf(u, v));
        p = (m8 & (1u << i)) ? p : 0.0f;
        af[i] = f2bf_fast(p);
    }
    acc[0] = __builtin_amdgcn_mfma_f32_16x16x32_bf16(af, b0, acc[0], 0, 0, 0);
    acc[1] = __builtin_amdgcn_mfma_f32_16x16x32_bf16(af, b1, acc[1], 0, 0, 0);
    acc[2] = __builtin_amdgcn_mfma_f32_16x16x32_bf16(af, b2, acc[2], 0, 0, 0);
    acc[3] = __builtin_amdgcn_mfma_f32_16x16x32_bf16(af, b3, acc[3], 0, 0, 0);
    acc[4] = __builtin_amdgcn_mfma_f32_16x16x32_bf16(af, b4, acc[4], 0, 0, 0);
    acc[5] = __builtin_amdgcn_mfma_f32_16x16x32_bf16(af, b5, acc[5], 0, 0, 0);
    acc[6] = __builtin_amdgcn_mfma_f32_16x16x32_bf16(af, b6, acc[6], 0, 0, 0);
    acc[7] = __builtin_amdgcn_mfma_f32_16x16x32_bf16(af, b7, acc[7], 0, 0, 0);
    acc[8] = __builtin_amdgcn_mfma_f32_16x16x32_bf16(af, ones, acc[8], 0, 0, 0);
}

// One pipeline step (64 cols): consume masks (LDS, written last step) +
// f2 (LDS); cooperatively load next step's adj slice (full-line coalesced)
// + WhT tile into regs; bodies; pack masks + ds_write tile for next step;
// one lgkm-only barrier.
#define GAT_STEP(KOFF, LRD0, LRD1, BUFW, MCUR, MNXT)                               \
    {                                                                              \
        const int koff_ = (KOFF);                                                  \
        unsigned m0 = (MCUR)[cofs0];                                               \
        unsigned m1 = (MCUR)[cofs1];                                               \
        float4 fa0 = *(const float4*)(lf2 + koff_);                                \
        float4 fb0 = *(const float4*)(lf2 + koff_ + 4);                            \
        float4 fa1 = *(const float4*)(lf2 + koff_ + 32);                           \
        float4 fb1 = *(const float4*)(lf2 + koff_ + 36);                           \
        const int kst_ = (koff_ + 64 < kchunk) ? koff_ + 64 : 0;                   \
        i32x4 xa0 = *(const i32x4*)(adjp0 + kst_);                                 \
        i32x4 xa1 = *(const i32x4*)(adjp0 + kst_ + 4);                             \
        i32x4 xb0 = *(const i32x4*)(adjp1 + kst_);                                 \
        i32x4 xb1 = *(const i32x4*)(adjp1 + kst_ + 4);                             \
        short8 r0 = *(const short8*)(g00 + kst_);                                  \
        short8 r1 = *(const short8*)(g01 + kst_);                                  \
        short8 r2 = *(const short8*)(g10 + kst_);                                  \
        short8 r3 = *(const short8*)(g11 + kst_);                                  \
        gat_body(LRD0, m0, fa0, fb0, c1, c2, acc, ones);                           \
        gat_body(LRD1, m1, fa1, fb1, c1, c2, acc, ones);                           \
        (MNXT)[pofs0] = (unsigned char)pack8(xa0, xa1);                            \
        (MNXT)[pofs1] = (unsigned char)pack8(xb0, xb1);                            \
        *(short8*)((BUFW) + d00) = r0;                                             \
        *(short8*)((BUFW) + d01) = r1;                                             \
        *(short8*)((BUFW) + d10) = r2;                                             \
        *(short8*)((BUFW) + d11) = r3;                                             \
        asm volatile("s_waitcnt lgkmcnt(0)" ::: "memory");                         \
        __builtin_amdgcn_s_barrier();                                              \
    }

// K2: fused adj-pack + mask + leaky_relu + exp + (P @ Wh). The 256 MB adj
// stream rides the latency-bound pipeline (block-cooperative full-line
// loads, VGPR pack, 1KB LDS mask double-buffer). gmax in prologue.
__global__ __launch_bounds__(256, 4) void k_attn(const int* __restrict__ adj,
                                                 const short* __restrict__ WhT,
                                                 const float* __restrict__ f1,
                                                 const float* __restrict__ f2,
                                                 short* __restrict__ numb,
                                                 float* __restrict__ denb,
                                                 int kchunk, int nsplit) {
    __shared__ __align__(16) short ldsW[2][8192];   // 32 KB: 2 x [128][64] swizzled
    __shared__ __align__(16) float ldsF2[1024];     // 4 KB: raw f2 slice
    __shared__ __align__(8) unsigned char mbuf[2][64][8];   // 1 KB: mask dbuf
    const int tid = threadIdx.x;
    const int lane = tid & 63;
    const int wave = tid >> 6;
    const int split = blockIdx.x & (nsplit - 1);
    const int rt = blockIdx.x / nsplit;
    const int rowbase0 = rt * 64;
    const int rowbase = rowbase0 + wave * 16;
    const int col = lane & 15;
    const int kg = lane >> 4;
    const int arow = rowbase + col;

    // ---- prologue A: block-local gmax over all f2 (L2-hot) ----
    float gm = -3.4e38f;
    for (int i = tid * 4; i < NN; i += 1024) {
        float4 v = *(const float4*)(f2 + i);
        gm = fmaxf(fmaxf(gm, fmaxf(v.x, v.y)), fmaxf(v.z, v.w));
    }
    #pragma unroll
    for (int s = 1; s <= 32; s <<= 1) gm = fmaxf(gm, __shfl_xor(gm, s, 64));
    if (lane == 0) ldsF2[wave] = gm;
    __syncthreads();
    gm = fmaxf(fmaxf(ldsF2[0], ldsF2[1]), fmaxf(ldsF2[2], ldsF2[3]));
    __syncthreads();                       // all reads done before ldsF2 reuse

    const float f1r = f1[arow];
    const float t0v = f1r + gm;
    const float mhat = fmaxf(t0v, LRELU_A * t0v);   // row-max upper bound
    const float mh2 = mhat * L2E;
    const float c1 = fmaf(f1r, L2E, -mh2);
    const float c2 = fmaf(LRELU_A * f1r, L2E, -mh2);

    const short8 ones = {0x3F80, 0x3F80, 0x3F80, 0x3F80,
                         0x3F80, 0x3F80, 0x3F80, 0x3F80};   // bf16 1.0

    const int kbase0 = split * kchunk;
    const float* lf2 = ldsF2 + kg * 8;

    // adj producer map: thread covers rows {prow, 32+prow}, cols pcq*8..+7
    // -> per instruction 8 lanes x 16B = 128B contiguous per row.
    const int prow = tid >> 3;              // 0..31
    const int pcq = tid & 7;                // 0..7
    const int* adjp0 = adj + (size_t)(rowbase0 + prow) * NN + kbase0 + pcq * 8;
    const int* adjp1 = adjp0 + (size_t)32 * NN;
    const int pofs0 = prow * 8 + pcq;
    const int pofs1 = (32 + prow) * 8 + pcq;
    // consumer offsets: row's 8-byte mask, byte kg (body0) / 4+kg (body1)
    const int rowc = wave * 16 + col;
    const int cofs0 = rowc * 8 + kg;
    const int cofs1 = rowc * 8 + 4 + kg;
    unsigned char* mb0 = &mbuf[0][0][0];
    unsigned char* mb1 = &mbuf[1][0][0];

    // full-line W staging: row = wave*32 + (lane>>2), 16 rows x 64B/inst.
    const int srow = wave * 32 + (lane >> 2);
    const int sx = srow & 7;
    const short* gsb = WhT + (size_t)srow * NN + kbase0 + (lane & 3) * 8;
    const short* g00 = gsb;
    const short* g01 = gsb + 32;
    const short* g10 = gsb + (size_t)16 * NN;
    const short* g11 = gsb + (size_t)16 * NN + 32;
    const int d00 = srow * 64        + ((((lane & 3) + 0) ^ sx) * 8);
    const int d01 = srow * 64        + ((((lane & 3) + 4) ^ sx) * 8);
    const int d10 = (srow + 16) * 64 + ((((lane & 3) + 0) ^ sx) * 8);
    const int d11 = (srow + 16) * 64 + ((((lane & 3) + 4) ^ sx) * 8);
    short* buf0 = &ldsW[0][0];
    short* buf1 = &ldsW[1][0];

    // compute-read bases (body0 / body1 within a 64-col tile)
    const short* lrdE0 = &ldsW[0][col * 64 + ((kg ^ (col & 7)) * 8)];
    const short* lrdE1 = &ldsW[0][col * 64 + (((kg ^ (col & 7)) * 8) ^ 32)];
    const short* lrdO0 = lrdE0 + 8192;
    const short* lrdO1 = lrdE1 + 8192;

    f32x4 acc[9] = {};

    // ---- prologue B: f2 slice -> LDS; W tile0 -> buf0; masks step0 -> mbuf0
    for (int i = tid * 4; i < kchunk; i += 1024)
        *(float4*)&ldsF2[i] = *(const float4*)(f2 + kbase0 + i);
    {
        short8 r0 = *(const short8*)(g00);
        short8 r1 = *(const short8*)(g01);
        short8 r2 = *(const short8*)(g10);
        short8 r3 = *(const short8*)(g11);
        *(short8*)(buf0 + d00) = r0;
        *(short8*)(buf0 + d01) = r1;
        *(short8*)(buf0 + d10) = r2;
        *(short8*)(buf0 + d11) = r3;
        i32x4 xa0 = *(const i32x4*)(adjp0);
        i32x4 xa1 = *(const i32x4*)(adjp0 + 4);
        i32x4 xb0 = *(const i32x4*)(adjp1);
        i32x4 xb1 = *(const i32x4*)(adjp1 + 4);
        mb0[pofs0] = (unsigned char)pack8(xa0, xa1);
        mb0[pofs1] = (unsigned char)pack8(xb0, xb1);
    }
    asm volatile("s_waitcnt lgkmcnt(0)" ::: "memory");
    __builtin_amdgcn_s_barrier();

    for (int koff = 0; koff < kchunk; koff += 128) {
        GAT_STEP(koff,      lrdE0, lrdE1, buf1, mb0, mb1);   // compute buf0
        GAT_STEP(koff + 64, lrdO0, lrdO1, buf0, mb1, mb0);   // compute buf1
    }

    const int rsub = (lane >> 4) * 4;
    // den = P @ ones: acc[8][r] holds den[rowbase+rsub+r]
    if (col == 0) {
        #pragma unroll
        for (int r = 0; r < 4; ++r)
            __builtin_nontemporal_store(acc[8][r],
                &denb[(size_t)split * NN + rowbase + rsub + r]);
    }
    short* np = numb + ((size_t)split * NN + rowbase) * FOUT;
    #pragma unroll
    for (int t = 0; t < 8; ++t) {
        #pragma unroll
        for (int r = 0; r < 4; ++r) {
            __builtin_nontemporal_store(f2bf_fast(acc[t][r]),
                &np[(size_t)(rsub + r) * FOUT + t * 16 + col]);
        }
    }
}

// K3: sum bf16 split partials, divide, ELU. One short8 numb load per split
// per thread (8 outputs/thread), f32x4 out stores.
__global__ __launch_bounds__(256) void k_final(const short* __restrict__ numb,
                                               const float* __restrict__ denb,
                                               float* __restrict__ out,
                                               int splitk) {
    const int idx8 = blockIdx.x * 256 + threadIdx.x;   // one per 8 cols
    const int row = idx8 >> 4;
    const int cg = (idx8 & 15) * 8;
    float s[8] = {0.f, 0.f, 0.f, 0.f, 0.f, 0.f, 0.f, 0.f};
    float d = 0.0f;
    for (int sp = 0; sp < splitk; ++sp) {
        short8 v = __builtin_nontemporal_load(
            (const short8*)&numb[((size_t)sp * NN + row) * FOUT + cg]);
        #pragma unroll
        for (int j = 0; j < 8; ++j) s[j] += bf2f(v[j]);
        d += denb[(size_t)sp * NN + row];
    }
    const float rd = 1.0f / d;
    f32x4 o0, o1;
    #pragma unroll
    for (int j = 0; j < 4; ++j) {
        float v = s[j] * rd;
        o0[j] = v > 0.0f ? v : expm1f(v);
    }
    #pragma unroll
    for (int j = 0; j < 4; ++j) {
        float v = s[4 + j] * rd;
        o1[j] = v > 0.0f ? v : expm1f(v);
    }
    float* op = out + (size_t)row * FOUT + cg;
    __builtin_nontemporal_store(o0, (f32x4*)op);
    __builtin_nontemporal_store(o1, (f32x4*)(op + 4));
}

extern "C" void kernel_launch(void* const* d_in, const int* in_sizes, int n_in,
                              void* d_out, int out_size, void* d_ws, size_t ws_size,
                              hipStream_t stream) {
    const float* h = (const float*)d_in[0];
    const int* adj = (const int*)d_in[1];
    const float* W = (const float*)d_in[2];
    const float* a = (const float*)d_in[3];
    float* out = (float*)d_out;

    char* ws = (char*)d_ws;
    size_t off = 0;
    auto alloc = [&](size_t nbytes) {
        char* p = ws + off;
        off = (off + nbytes + 255) & ~(size_t)255;
        return p;
    };
    short* WhT = (short*)alloc((size_t)FOUT * NN * 2);
    float* f1  = (float*)alloc(NN * 4);
    float* f2  = (float*)alloc(NN * 4);

    const int splitk = 8;                   // kchunk = 1024 matches ldsF2[1024]
    short* numb = (short*)alloc((size_t)splitk * NN * FOUT * 2);   // bf16 partials
    float* denb = (float*)alloc((size_t)splitk * NN * 4);
    const int kchunk = NN / splitk;

    k_prep<<<NN / 8, 256, 0, stream>>>(h, W, a, WhT, f1, f2);
    k_attn<<<(NN / 64) * splitk, 256, 0, stream>>>(adj, WhT, f1, f2, numb, denb,
                                                   kchunk, splitk);
    k_final<<<NN * FOUT / 8 / 256, 256, 0, stream>>>(numb, denb, out, splitk);
}

// Round 21
// 116.377 us; speedup vs baseline: 1.2013x; 1.2013x over previous
//
#include <hip/hip_runtime.h>
#include <hip/hip_bf16.h>
#include <math.h>

typedef short short8 __attribute__((ext_vector_type(8)));
typedef float f32x4 __attribute__((ext_vector_type(4)));
typedef int i32x4 __attribute__((ext_vector_type(4)));

#define NN 8192
#define FIN 256
#define FOUT 128
#define LRELU_A 0.2f
#define L2E 1.44269504088896f

__device__ __forceinline__ short f2bf(float x) {
    unsigned u = __builtin_bit_cast(unsigned, x);
    unsigned r = (u + 0x7FFFu + ((u >> 16) & 1u)) >> 16;   // RNE
    return (short)r;
}

__device__ __forceinline__ short f2bf_fast(float x) {
    return __builtin_bit_cast(short, __float2bfloat16(x));
}

__device__ __forceinline__ float bf2f(short s) {
    return __builtin_bit_cast(float, (int)((unsigned short)s) << 16);
}

// K1: heterogeneous prep. Blocks [0,1024): Wh = h@W -> WhT bf16 (LDS-transposed,
// coalesced 16B writes; XCD-swizzled rows) + f1/f2. Blocks [1024, 9216):
// pack one adj row -> bitmask (HBM-bound). Co-resident streams overlap.
__global__ __launch_bounds__(256) void k_prep(const float* __restrict__ h,
                                              const float* __restrict__ W,
                                              const float* __restrict__ a,
                                              const int* __restrict__ adj,
                                              short* __restrict__ WhT,
                                              float* __restrict__ f1,
                                              float* __restrict__ f2,
                                              unsigned* __restrict__ packed) {
    __shared__ float hs[8][FIN];
    __shared__ unsigned char nib[2048];
    const int tid = threadIdx.x;
    const int bid = blockIdx.x;

    if (bid >= NN / 8) {
        // ---- pack part: one adj row, fully coalesced ----
        const int row = bid - NN / 8;
        const i32x4* base = (const i32x4*)(adj + (size_t)row * NN);
        #pragma unroll
        for (int q = 0; q < 8; ++q) {
            int idx = q * 256 + tid;
            i32x4 v = __builtin_nontemporal_load(base + idx);
            unsigned b = (unsigned)(v.x & 1)        | ((unsigned)(v.y & 1) << 1) |
                         ((unsigned)(v.z & 1) << 2) | ((unsigned)(v.w & 1) << 3);
            nib[idx] = (unsigned char)b;
        }
        __syncthreads();
        unsigned long long n8 = *(const unsigned long long*)&nib[tid * 8];
        unsigned w = 0;
        #pragma unroll
        for (int j = 0; j < 8; ++j)
            w |= ((unsigned)((n8 >> (8 * j)) & 0xFull)) << (4 * j);
        packed[(size_t)row * (NN / 32) + tid] = w;
        return;
    }

    // ---- Wh part: 8 rows; XCD-swizzled row mapping ----
    const int swz = (bid & 7) * 128 + (bid >> 3);   // bijective on [0,1024)
    const int r0 = swz * 8;
    #pragma unroll
    for (int i = 0; i < 2; ++i) {
        int f4 = tid + 256 * i;
        int row = f4 >> 6;
        int k4 = (f4 & 63) << 2;
        *(float4*)&hs[row][k4] = *(const float4*)(h + (size_t)(r0 + row) * FIN + k4);
    }
    __syncthreads();
    const int c4 = (tid & 31) * 4;
    const int row = tid >> 5;
    float acc0 = 0.f, acc1 = 0.f, acc2 = 0.f, acc3 = 0.f;
    #pragma unroll 4
    for (int k = 0; k < FIN; ++k) {
        float hv = hs[row][k];
        float4 w4 = *(const float4*)(W + (size_t)k * FOUT + c4);
        acc0 = fmaf(hv, w4.x, acc0);
        acc1 = fmaf(hv, w4.y, acc1);
        acc2 = fmaf(hv, w4.z, acc2);
        acc3 = fmaf(hv, w4.w, acc3);
    }
    const int wr = r0 + row;

    // transpose through LDS (reuse hs): tws[col][row8], then 16B writes
    __syncthreads();                      // all hs reads complete
    short (*tws)[8] = (short (*)[8])hs;
    tws[c4 + 0][row] = f2bf(acc0);
    tws[c4 + 1][row] = f2bf(acc1);
    tws[c4 + 2][row] = f2bf(acc2);
    tws[c4 + 3][row] = f2bf(acc3);

    float4 a1v = *(const float4*)(a + c4);
    float4 a2v = *(const float4*)(a + FOUT + c4);
    float p1 = acc0 * a1v.x + acc1 * a1v.y + acc2 * a1v.z + acc3 * a1v.w;
    float p2 = acc0 * a2v.x + acc1 * a2v.y + acc2 * a2v.z + acc3 * a2v.w;
    #pragma unroll
    for (int m = 1; m <= 16; m <<= 1) {
        p1 += __shfl_xor(p1, m, 64);
        p2 += __shfl_xor(p2, m, 64);
    }
    if ((tid & 31) == 0) {
        f1[wr] = p1;
        f2[wr] = p2;
    }

    __syncthreads();                      // tws writes complete
    if (tid < FOUT)
        *(short8*)(WhT + (size_t)tid * NN + r0) = *(const short8*)tws[tid];
}

// body: 32 cols. fv = raw f2. u = fma(L2E,fv,c1), v = fma(0.2*L2E,fv,c2),
// p = exp2(max(u,v)), mask, bf16; 8 MFMA + 1 ones-MFMA (den = P@1).
__device__ __forceinline__ void gat_body(const short* __restrict__ lrd, unsigned m8,
                                         float4 fa, float4 fb,
                                         float c1, float c2,
                                         f32x4 acc[9], short8 ones) {
    short8 b0 = *(const short8*)(lrd + 0 * 1024);
    short8 b1 = *(const short8*)(lrd + 1 * 1024);
    short8 b2 = *(const short8*)(lrd + 2 * 1024);
    short8 b3 = *(const short8*)(lrd + 3 * 1024);
    short8 b4 = *(const short8*)(lrd + 4 * 1024);
    short8 b5 = *(const short8*)(lrd + 5 * 1024);
    short8 b6 = *(const short8*)(lrd + 6 * 1024);
    short8 b7 = *(const short8*)(lrd + 7 * 1024);

    float fv[8] = {fa.x, fa.y, fa.z, fa.w, fb.x, fb.y, fb.z, fb.w};
    short8 af;
    #pragma unroll
    for (int i = 0; i < 8; ++i) {
        float u = fmaf(L2E, fv[i], c1);
        float v = fmaf(LRELU_A * L2E, fv[i], c2);
        float p = __builtin_amdgcn_exp2f(fmaxf(u, v));
        p = (m8 & (1u << i)) ? p : 0.0f;
        af[i] = f2bf_fast(p);
    }
    acc[0] = __builtin_amdgcn_mfma_f32_16x16x32_bf16(af, b0, acc[0], 0, 0, 0);
    acc[1] = __builtin_amdgcn_mfma_f32_16x16x32_bf16(af, b1, acc[1], 0, 0, 0);
    acc[2] = __builtin_amdgcn_mfma_f32_16x16x32_bf16(af, b2, acc[2], 0, 0, 0);
    acc[3] = __builtin_amdgcn_mfma_f32_16x16x32_bf16(af, b3, acc[3], 0, 0, 0);
    acc[4] = __builtin_amdgcn_mfma_f32_16x16x32_bf16(af, b4, acc[4], 0, 0, 0);
    acc[5] = __builtin_amdgcn_mfma_f32_16x16x32_bf16(af, b5, acc[5], 0, 0, 0);
    acc[6] = __builtin_amdgcn_mfma_f32_16x16x32_bf16(af, b6, acc[6], 0, 0, 0);
    acc[7] = __builtin_amdgcn_mfma_f32_16x16x32_bf16(af, b7, acc[7], 0, 0, 0);
    acc[8] = __builtin_amdgcn_mfma_f32_16x16x32_bf16(af, ones, acc[8], 0, 0, 0);
}

// One pipeline step (64 cols): masks from packed word pair (prefetched last
// step); stage next WhT tile (full-line reg loads -> ds_write at step end);
// raw f2 from LDS; one lgkm-only barrier per step.
#define GAT_STEP(KOFF, MC, LRD0, LRD1, BUFW)                                       \
    {                                                                              \
        const int koff_ = (KOFF);                                                  \
        float4 fa0 = *(const float4*)(lf2 + koff_);                                \
        float4 fb0 = *(const float4*)(lf2 + koff_ + 4);                            \
        float4 fa1 = *(const float4*)(lf2 + koff_ + 32);                           \
        float4 fb1 = *(const float4*)(lf2 + koff_ + 36);                           \
        unsigned m0 = (MC.x >> mshift) & 0xffu;                                    \
        unsigned m1 = (MC.y >> mshift) & 0xffu;                                    \
        const int kpm_ = (koff_ + 128 < kchunk) ? koff_ + 128 : 0;                 \
        MC = *(const uint2*)(pkrow + (kpm_ >> 5));                                 \
        const int kst_ = (koff_ + 64 < kchunk) ? koff_ + 64 : 0;                   \
        short8 r0 = *(const short8*)(g00 + kst_);                                  \
        short8 r1 = *(const short8*)(g01 + kst_);                                  \
        short8 r2 = *(const short8*)(g10 + kst_);                                  \
        short8 r3 = *(const short8*)(g11 + kst_);                                  \
        gat_body(LRD0, m0, fa0, fb0, c1, c2, acc, ones);                           \
        gat_body(LRD1, m1, fa1, fb1, c1, c2, acc, ones);                           \
        *(short8*)((BUFW) + d00) = r0;                                             \
        *(short8*)((BUFW) + d01) = r1;                                             \
        *(short8*)((BUFW) + d10) = r2;                                             \
        *(short8*)((BUFW) + d11) = r3;                                             \
        asm volatile("s_waitcnt lgkmcnt(0)" ::: "memory");                         \
        __builtin_amdgcn_s_barrier();                                              \
    }

// K2: fused mask + leaky_relu + exp + (P @ Wh) via mfma_f32_16x16x32_bf16.
// gmax in prologue (L2-hot scan, no fences); numb partials stored as bf16.
__global__ __launch_bounds__(256, 4) void k_attn(const unsigned* __restrict__ packed,
                                                 const short* __restrict__ WhT,
                                                 const float* __restrict__ f1,
                                                 const float* __restrict__ f2,
                                                 short* __restrict__ numb,
                                                 float* __restrict__ denb,
                                                 int kchunk, int nsplit) {
    __shared__ __align__(16) short ldsW[2][8192];   // 2 x [128 rows][64 cols], swizzled
    __shared__ __align__(16) float ldsF2[2048];     // raw f2
    const int tid = threadIdx.x;
    const int lane = tid & 63;
    const int wave = tid >> 6;
    const int split = blockIdx.x & (nsplit - 1);
    const int rt = blockIdx.x / nsplit;
    const int rowbase = rt * 64 + wave * 16;
    const int col = lane & 15;
    const int kg = lane >> 4;
    const int arow = rowbase + col;

    // ---- prologue A: block-local gmax over all f2 (L2-hot) ----
    float gm = -3.4e38f;
    for (int i = tid * 4; i < NN; i += 1024) {
        float4 v = *(const float4*)(f2 + i);
        gm = fmaxf(fmaxf(gm, fmaxf(v.x, v.y)), fmaxf(v.z, v.w));
    }
    #pragma unroll
    for (int s = 1; s <= 32; s <<= 1) gm = fmaxf(gm, __shfl_xor(gm, s, 64));
    if (lane == 0) ldsF2[wave] = gm;
    __syncthreads();
    gm = fmaxf(fmaxf(ldsF2[0], ldsF2[1]), fmaxf(ldsF2[2], ldsF2[3]));
    __syncthreads();                       // all reads done before ldsF2 reuse

    const float f1r = f1[arow];
    const float t0v = f1r + gm;
    const float mhat = fmaxf(t0v, LRELU_A * t0v);   // row-max upper bound
    const float mh2 = mhat * L2E;
    const float c1 = fmaf(f1r, L2E, -mh2);
    const float c2 = fmaf(LRELU_A * f1r, L2E, -mh2);

    const short8 ones = {0x3F80, 0x3F80, 0x3F80, 0x3F80,
                         0x3F80, 0x3F80, 0x3F80, 0x3F80};   // bf16 1.0

    const int kbase0 = split * kchunk;
    const unsigned* pkrow = packed + (size_t)arow * (NN / 32) + (kbase0 >> 5);
    const int mshift = kg * 8;
    const float* lf2 = ldsF2 + kg * 8;

    // full-line W staging: row = wave*32 + (lane>>2), 16 rows x 64B/inst.
    const int srow = wave * 32 + (lane >> 2);
    const int sx = srow & 7;
    const short* gsb = WhT + (size_t)srow * NN + kbase0 + (lane & 3) * 8;
    const short* g00 = gsb;
    const short* g01 = gsb + 32;
    const short* g10 = gsb + (size_t)16 * NN;
    const short* g11 = gsb + (size_t)16 * NN + 32;
    const int d00 = srow * 64        + ((((lane & 3) + 0) ^ sx) * 8);
    const int d01 = srow * 64        + ((((lane & 3) + 4) ^ sx) * 8);
    const int d10 = (srow + 16) * 64 + ((((lane & 3) + 0) ^ sx) * 8);
    const int d11 = (srow + 16) * 64 + ((((lane & 3) + 4) ^ sx) * 8);
    short* buf0 = &ldsW[0][0];
    short* buf1 = &ldsW[1][0];

    // compute-read bases (body0 / body1 within a 64-col tile)
    const short* lrdE0 = &ldsW[0][col * 64 + ((kg ^ (col & 7)) * 8)];
    const short* lrdE1 = &ldsW[0][col * 64 + (((kg ^ (col & 7)) * 8) ^ 32)];
    const short* lrdO0 = lrdE0 + 8192;
    const short* lrdO1 = lrdE1 + 8192;

    f32x4 acc[9] = {};

    // ---- prologue B: raw f2 -> LDS; W tile0 -> buf0; masks for tiles 0,1 ----
    for (int i = tid * 4; i < kchunk; i += 1024)
        *(float4*)&ldsF2[i] = *(const float4*)(f2 + kbase0 + i);
    {
        short8 r0 = *(const short8*)(g00);
        short8 r1 = *(const short8*)(g01);
        short8 r2 = *(const short8*)(g10);
        short8 r3 = *(const short8*)(g11);
        *(short8*)(buf0 + d00) = r0;
        *(short8*)(buf0 + d01) = r1;
        *(short8*)(buf0 + d10) = r2;
        *(short8*)(buf0 + d11) = r3;
    }
    uint2 mA = *(const uint2*)(pkrow);
    uint2 mB = *(const uint2*)(pkrow + 2);
    asm volatile("s_waitcnt lgkmcnt(0)" ::: "memory");
    __builtin_amdgcn_s_barrier();

    for (int koff = 0; koff < kchunk; koff += 128) {
        GAT_STEP(koff,      mA, lrdE0, lrdE1, buf1);   // compute buf0, stage buf1
        GAT_STEP(koff + 64, mB, lrdO0, lrdO1, buf0);   // compute buf1, stage buf0
    }

    const int rsub = (lane >> 4) * 4;
    // den = P @ ones: acc[8][r] holds den[rowbase+rsub+r]
    if (col == 0) {
        #pragma unroll
        for (int r = 0; r < 4; ++r)
            __builtin_nontemporal_store(acc[8][r],
                &denb[(size_t)split * NN + rowbase + rsub + r]);
    }
    short* np = numb + ((size_t)split * NN + rowbase) * FOUT;
    #pragma unroll
    for (int t = 0; t < 8; ++t) {
        #pragma unroll
        for (int r = 0; r < 4; ++r) {
            __builtin_nontemporal_store(f2bf_fast(acc[t][r]),
                &np[(size_t)(rsub + r) * FOUT + t * 16 + col]);
        }
    }
}

// K3: sum bf16 split partials, divide, ELU. One short8 numb load per split
// per thread (8 outputs/thread), f32x4 out stores.
__global__ __launch_bounds__(256) void k_final(const short* __restrict__ numb,
                                               const float* __restrict__ denb,
                                               float* __restrict__ out,
                                               int splitk) {
    const int idx8 = blockIdx.x * 256 + threadIdx.x;   // one per 8 cols
    const int row = idx8 >> 4;
    const int cg = (idx8 & 15) * 8;
    float s[8] = {0.f, 0.f, 0.f, 0.f, 0.f, 0.f, 0.f, 0.f};
    float d = 0.0f;
    for (int sp = 0; sp < splitk; ++sp) {
        short8 v = __builtin_nontemporal_load(
            (const short8*)&numb[((size_t)sp * NN + row) * FOUT + cg]);
        #pragma unroll
        for (int j = 0; j < 8; ++j) s[j] += bf2f(v[j]);
        d += denb[(size_t)sp * NN + row];
    }
    const float rd = 1.0f / d;
    f32x4 o0, o1;
    #pragma unroll
    for (int j = 0; j < 4; ++j) {
        float v = s[j] * rd;
        o0[j] = v > 0.0f ? v : expm1f(v);
    }
    #pragma unroll
    for (int j = 0; j < 4; ++j) {
        float v = s[4 + j] * rd;
        o1[j] = v > 0.0f ? v : expm1f(v);
    }
    float* op = out + (size_t)row * FOUT + cg;
    __builtin_nontemporal_store(o0, (f32x4*)op);
    __builtin_nontemporal_store(o1, (f32x4*)(op + 4));
}

extern "C" void kernel_launch(void* const* d_in, const int* in_sizes, int n_in,
                              void* d_out, int out_size, void* d_ws, size_t ws_size,
                              hipStream_t stream) {
    const float* h = (const float*)d_in[0];
    const int* adj = (const int*)d_in[1];
    const float* W = (const float*)d_in[2];
    const float* a = (const float*)d_in[3];
    float* out = (float*)d_out;

    char* ws = (char*)d_ws;
    size_t off = 0;
    auto alloc = [&](size_t nbytes) {
        char* p = ws + off;
        off = (off + nbytes + 255) & ~(size_t)255;
        return p;
    };
    short* WhT     = (short*)alloc((size_t)FOUT * NN * 2);
    float* f1      = (float*)alloc(NN * 4);
    float* f2      = (float*)alloc(NN * 4);
    unsigned* pkd  = (unsigned*)alloc((size_t)NN * (NN / 32) * 4);   // 8 MB

    int splitk = 8;
    while (splitk > 1 &&
           off + (size_t)splitk * ((size_t)NN * FOUT * 2 + NN * 4 + 512) > ws_size)
        splitk >>= 1;
    short* numb = (short*)alloc((size_t)splitk * NN * FOUT * 2);    // bf16 partials
    float* denb = (float*)alloc((size_t)splitk * NN * 4);
    const int kchunk = NN / splitk;

    k_prep<<<NN / 8 + NN, 256, 0, stream>>>(h, W, a, adj, WhT, f1, f2, pkd);
    k_attn<<<(NN / 64) * splitk, 256, 0, stream>>>(pkd, WhT, f1, f2, numb, denb,
                                                   kchunk, splitk);
    k_final<<<NN * FOUT / 8 / 256, 256, 0, stream>>>(numb, denb, out, splitk);
}